// Round 11
// baseline (112.757 us; speedup 1.0000x reference)
//
#include <hip/hip_runtime.h>

typedef int v4i __attribute__((ext_vector_type(4)));

#define NIMG 32
#define CIN  256
#define COUT 256
#define HW   3136   // 56*56
#define W56  56
#define HP   58     // padded H/W
#define PIMG (HP * HP)                       // 3364
#define XQP_BYTES (NIMG * PIMG * CIN)        // 27,557,888
#define WP_BYTES  (9 * COUT * CIN)           // 589,824

#define BARRIER() asm volatile("s_barrier" ::: "memory")
#define VMCNT0()  asm volatile("s_waitcnt vmcnt(0)" ::: "memory")

// ---------------------------------------------------------------------------
// Kernel 0: zero only the pad border (228 px/image * 256B)
// ---------------------------------------------------------------------------
__global__ __launch_bounds__(256) void zero_border(v4i* __restrict__ p)
{
    int i = blockIdx.x * 256 + threadIdx.x;
    if (i >= NIMG * 228 * 16) return;
    int n = i / 3648, r = i % 3648, pix = r >> 4, c = r & 15;
    int h, w;
    if (pix < 58)       { h = 0;         w = pix;       }
    else if (pix < 116) { h = 57;        w = pix - 58;  }
    else if (pix < 172) { h = pix - 115; w = 0;         }
    else                { h = pix - 171; w = 57;        }
    v4i z = {0, 0, 0, 0};
    p[(size_t)(n * PIMG + h * HP + w) * 16 + c] = z;
}

// ---------------------------------------------------------------------------
// Kernel 1: quantize + transpose  NCHW f32 -> padded NHWC int8 (interior)
// ---------------------------------------------------------------------------
__global__ __launch_bounds__(256) void quantize_pad(
    const float* __restrict__ x, signed char* __restrict__ xqp)
{
    __shared__ int tile[64][65];
    const int n  = blockIdx.z;
    const int c0 = blockIdx.y * 64;
    const int p0 = blockIdx.x * 64;
    const int tid = threadIdx.x;

    const int px   = tid & 63;
    const int crow = tid >> 6;
    const float* xb = x + ((size_t)(n * CIN + c0)) * HW + p0;
#pragma unroll
    for (int i = 0; i < 16; ++i) {
        int c = crow + i * 4;
        float v = xb[(size_t)c * HW + px];
        v = fminf(fmaxf(v, -1.f), 1.f);
        tile[c][px] = (int)rintf(v * 127.f);
    }
    __syncthreads();

    const int c4   = tid & 15;
    const int prow = tid >> 4;
#pragma unroll
    for (int i = 0; i < 4; ++i) {
        int p  = prow + i * 16;
        int hw = p0 + p;
        int oh = hw / W56, ow = hw % W56;
        int b0 = tile[c4 * 4 + 0][p] & 255;
        int b1 = tile[c4 * 4 + 1][p] & 255;
        int b2 = tile[c4 * 4 + 2][p] & 255;
        int b3 = tile[c4 * 4 + 3][p] & 255;
        int packed = b0 | (b1 << 8) | (b2 << 16) | (b3 << 24);
        *(int*)(xqp + ((size_t)(n * PIMG + (oh + 1) * HP + (ow + 1))) * CIN
                    + c0 + c4 * 4) = packed;
    }
}

// ---------------------------------------------------------------------------
// Kernel 2: weight repack  OIHW int32{-1,0,1} -> [step 0..35][cout 256][64B]
// ---------------------------------------------------------------------------
__global__ __launch_bounds__(256) void repack_w(
    const int* __restrict__ wq, signed char* __restrict__ wp2)
{
    int idx  = blockIdx.x * 256 + threadIdx.x;   // < 589824
    int t    = idx >> 16;
    int rem  = idx & 65535;
    int kc   = rem >> 14;
    int rem2 = rem & 16383;
    int co   = rem2 >> 6;
    int c6   = rem2 & 63;
    int ci   = kc * 64 + c6;
    wp2[idx] = (signed char)wq[(co * CIN + ci) * 9 + t];
}

// ---------------------------------------------------------------------------
// Kernel 3: implicit-GEMM conv with 1-step REGISTER fragment pipeline:
// per step: {stage(s+2) gll | ds_read frags(s+1) (consumed NEXT step, latency
// hidden under MFMA) | 16 MFMA on frags(s) | vmcnt0 | barrier}.
// Tile 128x128, 4 waves of 64x64, ring-3 LDS (48KB), R5-proven swizzle.
// ---------------------------------------------------------------------------
__device__ __forceinline__ void gll16(const void* g, void* l)
{
    __builtin_amdgcn_global_load_lds(
        (const __attribute__((address_space(1))) int*)g,
        (__attribute__((address_space(3))) int*)l, 16, 0, 0);
}

__device__ __forceinline__ int boffset(int ss)   // substep 0..35
{
    int t9 = ss >> 2, kc = ss & 3;
    return ((t9 / 3 - 1) * HP + (t9 % 3 - 1)) * CIN + kc * 64;
}

__global__ __launch_bounds__(256) void bitconv_mfma(
    const signed char* __restrict__ xqp, const signed char* __restrict__ wp2,
    const float* __restrict__ s_, const float* __restrict__ bias,
    const float* __restrict__ act_s_p, float* __restrict__ out)
{
    // per buffer: A 8KB (128 cout x 64B) + B 8KB (128 px x 64B)
    __shared__ signed char lds[3][16384];

    const int tid  = threadIdx.x;
    const int lane = tid & 63;
    const int wid  = tid >> 6;          // 0..3
    const int wr   = wid >> 1;          // cout half
    const int wc   = wid & 1;           // px half
    const int l15  = lane & 15;
    const int kg   = lane >> 4;
    const int kgs  = ((kg ^ ((l15 >> 1) & 3)) << 4);   // swizzled chunk

    // XCD-bijective swizzle (1568 % 8 == 0)
    const int b  = blockIdx.x;
    const int w  = (b & 7) * 196 + (b >> 3);
    const int px0   = (w >> 1) * 128;
    const int cout0 = (w & 1) * 128;

    // ---- staging addresses (swizzle baked into the global source) ----
    const int srow   = tid >> 2;                         // 0..63
    const int schunk = (((tid & 3) ^ ((tid >> 3) & 3)) << 4);
    const signed char* asrc = wp2 + cout0 * 64 + srow * 64 + schunk;

    const signed char* bsrc[2];
#pragma unroll
    for (int r = 0; r < 2; ++r) {
        int p = px0 + srow + r * 64;
        int n = p / HW, q = p % HW;
        bsrc[r] = xqp
            + ((size_t)(n * PIMG + (q / W56 + 1) * HP + (q % W56 + 1))) * CIN
            + schunk;
    }

    // ---- fragment ds_read offsets (swizzled) ----
    int aoff[4], boff[4];
#pragma unroll
    for (int i = 0; i < 4; ++i)
        aoff[i] = (wr * 64 + i * 16 + l15) * 64 + kgs;
#pragma unroll
    for (int j = 0; j < 4; ++j)
        boff[j] = 8192 + (wc * 64 + j * 16 + l15) * 64 + kgs;

    v4i acc[4][4] = {};
    v4i fa[2][4], fb[2][4];             // register fragment double-buffer

    const int wb = wid * 1024;          // wave-uniform LDS sub-base

    auto stage = [&](int buf, int ss) { // 4 gll16 per thread: A 8K + B 8K
        signed char* L = &lds[buf][0];
        const signed char* a = asrc + ss * 16384;
        gll16(a,        L + wb);
        gll16(a + 4096, L + 4096 + wb);
        int bo = boffset(ss);
        gll16(bsrc[0] + bo, L + 8192  + wb);
        gll16(bsrc[1] + bo, L + 12288 + wb);
    };

    // ---- prologue: tiles 0,1 staged+drained; frags(0) -> regs ----
    stage(0, 0);
    stage(1, 1);
    VMCNT0();
    BARRIER();
#pragma unroll
    for (int i = 0; i < 4; ++i) fa[0][i] = *(const v4i*)(&lds[0][0] + aoff[i]);
#pragma unroll
    for (int j = 0; j < 4; ++j) fb[0][j] = *(const v4i*)(&lds[0][0] + boff[j]);

    for (int it = 0; it < 6; ++it) {
#pragma unroll
        for (int u = 0; u < 6; ++u) {
            const int s  = it * 6 + u;
            const int cu = u & 1;           // static after unroll
            const int nx = cu ^ 1;
            const int nbf = (u + 1) % 3;    // buf holding tile s+1 (static)

            // stage tile s+2 (ring WAR: frags(s-1) consumed before last barrier)
            if (s < 34) stage((u + 2) % 3, s + 2);

            // issue frag reads for s+1; consumed after next barrier ->
            // latency + port time hide under this step's MFMA cluster
            if (s < 35) {
                const signed char* L = &lds[nbf][0];
#pragma unroll
                for (int i = 0; i < 4; ++i) fa[nx][i] = *(const v4i*)(L + aoff[i]);
#pragma unroll
                for (int j = 0; j < 4; ++j) fb[nx][j] = *(const v4i*)(L + boff[j]);
            }

            __builtin_amdgcn_s_setprio(1);
#pragma unroll
            for (int i = 0; i < 4; ++i)
#pragma unroll
                for (int j = 0; j < 4; ++j)
                    acc[i][j] = __builtin_amdgcn_mfma_i32_16x16x64_i8(
                        fa[cu][i], fb[cu][j], acc[i][j], 0, 0, 0);
            __builtin_amdgcn_s_setprio(0);

            if (s < 35) {
                VMCNT0();    // tile s+2's gll landed (issued ~1 MFMA cluster ago)
                BARRIER();   // all waves: tile s+1 frags read, tile s+2 visible
            }
        }
    }

    // ---- epilogue: y = acc * (act_s * s[c]) + bias[c], NCHW f32 ----
    const float a_s = act_s_p[0];
    int nn[4], hh[4];
#pragma unroll
    for (int j = 0; j < 4; ++j) {
        int op = px0 + wc * 64 + j * 16 + l15;
        nn[j] = op / HW;
        hh[j] = op % HW;
    }
#pragma unroll
    for (int i = 0; i < 4; ++i) {
        int cb = cout0 + wr * 64 + i * 16 + kg * 4;
        float sc[4], bi[4];
#pragma unroll
        for (int r = 0; r < 4; ++r) {
            sc[r] = a_s * s_[cb + r];
            bi[r] = bias[cb + r];
        }
#pragma unroll
        for (int j = 0; j < 4; ++j)
#pragma unroll
            for (int r = 0; r < 4; ++r)
                out[((size_t)(nn[j] * COUT + cb + r)) * HW + hh[j]] =
                    (float)acc[i][j][r] * sc[r] + bi[r];
    }
}

// ---------------------------------------------------------------------------
extern "C" void kernel_launch(void* const* d_in, const int* in_sizes, int n_in,
                              void* d_out, int out_size, void* d_ws, size_t ws_size,
                              hipStream_t stream)
{
    const float* x     = (const float*)d_in[0];
    const int*   w_q   = (const int*)d_in[1];
    const float* s     = (const float*)d_in[2];
    const float* bias  = (const float*)d_in[3];
    const float* act_s = (const float*)d_in[4];

    signed char* xqp = (signed char*)d_ws;
    signed char* wp2 = (signed char*)d_ws + XQP_BYTES;

    zero_border<<<(NIMG * 228 * 16 + 255) / 256, 256, 0, stream>>>((v4i*)xqp);
    quantize_pad<<<dim3(49, 4, NIMG), 256, 0, stream>>>(x, xqp);
    repack_w<<<dim3(WP_BYTES / 256), 256, 0, stream>>>(w_q, wp2);
    bitconv_mfma<<<dim3(1568), 256, 0, stream>>>(
        xqp, wp2, s, bias, act_s, (float*)d_out);
}

// Round 13
// 104.832 us; speedup vs baseline: 1.0756x; 1.0756x over previous
//
#include <hip/hip_runtime.h>

typedef int v4i __attribute__((ext_vector_type(4)));

#define NIMG 32
#define CIN  256
#define COUT 256
#define HW   3136   // 56*56
#define W56  56
#define WP_BYTES (9 * COUT * CIN)            // 589,824
#define RROWS 4                              // region rows (2 out + 2 halo)
#define RCOLS 58
#define RPIX  (RROWS * RCOLS)                // 232

// ---------------------------------------------------------------------------
// Kernel 1: weight repack  OIHW int32{-1,0,1} -> [step 0..35][cout 256][64B]
// step = tap*4 + kc  (kc = 64-channel chunk)
// ---------------------------------------------------------------------------
__global__ __launch_bounds__(256) void repack_w(
    const int* __restrict__ wq, signed char* __restrict__ wp2)
{
    int idx  = blockIdx.x * 256 + threadIdx.x;   // < 589824
    int t    = idx >> 16;
    int rem  = idx & 65535;
    int kc   = rem >> 14;
    int rem2 = rem & 16383;
    int co   = rem2 >> 6;
    int c6   = rem2 & 63;
    int ci   = kc * 64 + c6;
    wp2[idx] = (signed char)wq[(co * CIN + ci) * 9 + t];
}

// ---------------------------------------------------------------------------
// Kernel 2: FUSED quantize + implicit-GEMM conv.
// Block = 2 output rows (112 px) x 256 cout, one image. 512 thr = 8 waves.
// Prologue: quantize the 4x58x256 input region f32->int8 into persistent,
//   XOR-swizzled LDS (59.4 KB) via LDS-tile transpose.
// Main loop (NO barriers): 36 steps; B frags ds_read from persistent LDS;
//   A frags (per-wave-private 32 couts) global->VGPR with 1-step prefetch.
// ---------------------------------------------------------------------------
__global__ __launch_bounds__(512, 2) void bitconv_fused(
    const float* __restrict__ x, const signed char* __restrict__ wp2,
    const float* __restrict__ scale, const float* __restrict__ bias,
    const float* __restrict__ act_s_p, float* __restrict__ out)
{
    __shared__ signed char Bq[RPIX * 256];   // 59392 B, swizzled granules
    __shared__ int tile[64][65];             // 16640 B transpose scratch

    const int tid  = threadIdx.x;
    const int lane = tid & 63;
    const int wid  = tid >> 6;          // 0..7 (wave owns couts wid*32..+31)
    const int l15  = lane & 15;
    const int kg   = lane >> 4;

    // XCD swizzle: 896 blocks, contiguous tiles per XCD (halo/L2 locality)
    const int b  = blockIdx.x;
    const int w  = (b & 7) * 112 + (b >> 3);
    const int n  = w / 28;
    const int r0 = (w % 28) * 2;        // output row base (2 rows/block)

    // ================= quantize prologue =================
    {
        const float* xb = x + (size_t)n * CIN * HW;
        const int px = tid & 63, cr = tid >> 6;      // read roles
        const int c4 = tid & 15, pr = tid >> 4;      // write roles
        for (int cg = 0; cg < 4; ++cg) {
            for (int pt = 0; pt < 4; ++pt) {
                int pp  = pt * 64 + px;              // region pixel 0..255
                int row = pp / RCOLS + r0 - 1;
                int col = pp % RCOLS - 1;
                bool vld = (pp < RPIX) && (row >= 0) && (row < 56)
                                       && (col >= 0) && (col < 56);
                int hw = row * W56 + col;
#pragma unroll
                for (int i = 0; i < 8; ++i) {
                    int c = cg * 64 + cr + i * 8;
                    float f = vld ? xb[(size_t)c * HW + hw] : 0.f;
                    f = fminf(fmaxf(f, -1.f), 1.f);
                    tile[cr + i * 8][px] = (int)rintf(f * 127.f);
                }
                __syncthreads();
#pragma unroll
                for (int i = 0; i < 2; ++i) {
                    int px2 = pr + i * 32;
                    int pp2 = pt * 64 + px2;
                    if (pp2 < RPIX) {
                        int b0 = tile[c4 * 4 + 0][px2] & 255;
                        int b1 = tile[c4 * 4 + 1][px2] & 255;
                        int b2 = tile[c4 * 4 + 2][px2] & 255;
                        int b3 = tile[c4 * 4 + 3][px2] & 255;
                        int packed = b0 | (b1 << 8) | (b2 << 16) | (b3 << 24);
                        int coff = cg * 64 + c4 * 4;
                        int byte = pp2 * 256 + (coff ^ ((pp2 & 7) << 4));
                        *(int*)(Bq + byte) = packed;
                    }
                }
                __syncthreads();    // tile reuse; last iter: Bq visible to all
            }
        }
    }

    // ================= main loop (barrier-free) =================
    // B frag pixel bases: frag j covers output px j*16+l15
    int ppj[7];
#pragma unroll
    for (int j = 0; j < 7; ++j) {
        int opx  = j * 16 + l15;            // 0..111
        int orow = opx / 56, ocol = opx % 56;
        ppj[j] = (orow + 1) * RCOLS + (ocol + 1);
    }
    const int inner0 = kg * 16;

    // A: per-wave 32 couts, 2 frags of 16; per-lane 16B, coalesced 1KB/frag
    const signed char* ap = wp2 + (wid * 32 + l15) * 64 + kg * 16;

    v4i acc[2][7] = {};
    v4i a0 = *(const v4i*)(ap);
    v4i a1 = *(const v4i*)(ap + 1024);

    int step = 0;
    for (int dh = -1; dh <= 1; ++dh)
    for (int dw = -1; dw <= 1; ++dw) {
        const int pshift = dh * RCOLS + dw;
#pragma unroll
        for (int kc = 0; kc < 4; ++kc) {
            // prefetch next A (global, async under this step's work)
            int snext = step < 35 ? step + 1 : 35;
            const signed char* an = ap + snext * 16384;
            v4i n0 = *(const v4i*)(an);
            v4i n1 = *(const v4i*)(an + 1024);

            const int innerk = kc * 64 + inner0;
            __builtin_amdgcn_s_setprio(1);
#pragma unroll
            for (int j = 0; j < 7; ++j) {
                int pix = ppj[j] + pshift;
                v4i bb = *(const v4i*)(Bq + pix * 256
                                          + (innerk ^ ((pix & 7) << 4)));
                acc[0][j] = __builtin_amdgcn_mfma_i32_16x16x64_i8(
                    a0, bb, acc[0][j], 0, 0, 0);
                acc[1][j] = __builtin_amdgcn_mfma_i32_16x16x64_i8(
                    a1, bb, acc[1][j], 0, 0, 0);
            }
            __builtin_amdgcn_s_setprio(0);
            a0 = n0; a1 = n1;
            ++step;
        }
    }

    // ================= epilogue =================
    const float a_s = act_s_p[0];
    const int hw0 = r0 * W56;
#pragma unroll
    for (int i = 0; i < 2; ++i) {
        int cb = wid * 32 + i * 16 + kg * 4;
        float sc[4], bi[4];
#pragma unroll
        for (int r = 0; r < 4; ++r) {
            sc[r] = a_s * scale[cb + r];
            bi[r] = bias[cb + r];
        }
#pragma unroll
        for (int j = 0; j < 7; ++j) {
            int px = j * 16 + l15;
#pragma unroll
            for (int r = 0; r < 4; ++r)
                out[((size_t)(n * COUT + cb + r)) * HW + hw0 + px] =
                    (float)acc[i][j][r] * sc[r] + bi[r];
        }
    }
}

// ---------------------------------------------------------------------------
extern "C" void kernel_launch(void* const* d_in, const int* in_sizes, int n_in,
                              void* d_out, int out_size, void* d_ws, size_t ws_size,
                              hipStream_t stream)
{
    const float* x     = (const float*)d_in[0];
    const int*   w_q   = (const int*)d_in[1];
    const float* s     = (const float*)d_in[2];
    const float* bias  = (const float*)d_in[3];
    const float* act_s = (const float*)d_in[4];

    signed char* wp2 = (signed char*)d_ws;

    repack_w<<<dim3(WP_BYTES / 256), 256, 0, stream>>>(w_q, wp2);
    bitconv_fused<<<dim3(NIMG * 28), 512, 0, stream>>>(
        x, wp2, s, bias, act_s, (float*)d_out);
}

// Round 14
// 85.966 us; speedup vs baseline: 1.3116x; 1.2195x over previous
//
#include <hip/hip_runtime.h>

typedef int v4i __attribute__((ext_vector_type(4)));

#define NIMG 32
#define CIN  256
#define COUT 256
#define HW   3136   // 56*56
#define W56  56
#define HP   58     // padded H/W
#define PIMG (HP * HP)                       // 3364
#define WP_BYTES  (9 * COUT * CIN)           // 589,824 (wp2 FIRST in ws)
#define XQP_BYTES (NIMG * PIMG * CIN)        // 27,557,888
#define RBYTES    (4 * HP * 256)             // 59,392 region bytes

#define VMCNT0()  asm volatile("s_waitcnt vmcnt(0)" ::: "memory")

__device__ __forceinline__ void gll16(const void* g, void* l)
{
    __builtin_amdgcn_global_load_lds(
        (const __attribute__((address_space(1))) int*)g,
        (__attribute__((address_space(3))) int*)l, 16, 0, 0);
}

// ---------------------------------------------------------------------------
// Kernel 0: zero only the pad border (228 px/image * 256B)
// ---------------------------------------------------------------------------
__global__ __launch_bounds__(256) void zero_border(v4i* __restrict__ p)
{
    int i = blockIdx.x * 256 + threadIdx.x;
    if (i >= NIMG * 228 * 16) return;
    int n = i / 3648, r = i % 3648, pix = r >> 4, c = r & 15;
    int h, w;
    if (pix < 58)       { h = 0;         w = pix;       }
    else if (pix < 116) { h = 57;        w = pix - 58;  }
    else if (pix < 172) { h = pix - 115; w = 0;         }
    else                { h = pix - 171; w = 57;        }
    v4i z = {0, 0, 0, 0};
    p[(size_t)(n * PIMG + h * HP + w) * 16 + c] = z;
}

// ---------------------------------------------------------------------------
// Kernel 1: quantize + transpose  NCHW f32 -> padded NHWC int8 (interior)
// ---------------------------------------------------------------------------
__global__ __launch_bounds__(256) void quantize_pad(
    const float* __restrict__ x, signed char* __restrict__ xqp)
{
    __shared__ int tile[64][65];
    const int n  = blockIdx.z;
    const int c0 = blockIdx.y * 64;
    const int p0 = blockIdx.x * 64;
    const int tid = threadIdx.x;

    const int px   = tid & 63;
    const int crow = tid >> 6;
    const float* xb = x + ((size_t)(n * CIN + c0)) * HW + p0;
#pragma unroll
    for (int i = 0; i < 16; ++i) {
        int c = crow + i * 4;
        float v = xb[(size_t)c * HW + px];
        v = fminf(fmaxf(v, -1.f), 1.f);
        tile[c][px] = (int)rintf(v * 127.f);
    }
    __syncthreads();

    const int c4   = tid & 15;
    const int prow = tid >> 4;
#pragma unroll
    for (int i = 0; i < 4; ++i) {
        int p  = prow + i * 16;
        int hw = p0 + p;
        int oh = hw / W56, ow = hw % W56;
        int b0 = tile[c4 * 4 + 0][p] & 255;
        int b1 = tile[c4 * 4 + 1][p] & 255;
        int b2 = tile[c4 * 4 + 2][p] & 255;
        int b3 = tile[c4 * 4 + 3][p] & 255;
        int packed = b0 | (b1 << 8) | (b2 << 16) | (b3 << 24);
        *(int*)(xqp + ((size_t)(n * PIMG + (oh + 1) * HP + (ow + 1))) * CIN
                    + c0 + c4 * 4) = packed;
    }
}

// ---------------------------------------------------------------------------
// Kernel 2: weight repack  OIHW int32{-1,0,1} -> [step 0..35][cout 256][64B]
// ---------------------------------------------------------------------------
__global__ __launch_bounds__(256) void repack_w(
    const int* __restrict__ wq, signed char* __restrict__ wp2)
{
    int idx  = blockIdx.x * 256 + threadIdx.x;   // < 589824
    int t    = idx >> 16;
    int rem  = idx & 65535;
    int kc   = rem >> 14;
    int rem2 = rem & 16383;
    int co   = rem2 >> 6;
    int c6   = rem2 & 63;
    int ci   = kc * 64 + c6;
    wp2[idx] = (signed char)wq[(co * CIN + ci) * 9 + t];
}

// ---------------------------------------------------------------------------
// Kernel 3: B-stationary conv. Block = 256 cout x 112 px (2 out rows, 1 img).
// Stage 4x58x256 = 59KB xq region into LDS ONCE (swizzle-sourced gll16),
// then 36 steps with NO barriers / NO vmcnt / NO LDS writes:
//   per wave (64 couts): 7 swizzled B ds_read_b128 + 4 A global dwordx4
//   (1-step reg prefetch, L2-resident) -> 28 x mfma_i32_16x16x64_i8.
// ---------------------------------------------------------------------------
__global__ __launch_bounds__(256, 2) void bitconv_conv(
    const signed char* __restrict__ xqp, const signed char* __restrict__ wp2,
    const float* __restrict__ scale, const float* __restrict__ bias,
    const float* __restrict__ act_s_p, float* __restrict__ out)
{
    __shared__ signed char Bq[RBYTES];      // persistent region, swizzled

    const int tid  = threadIdx.x;
    const int lane = tid & 63;
    const int wid  = tid >> 6;          // 0..3  -> couts wid*64..+63
    const int l15  = lane & 15;
    const int kg   = lane >> 4;

    // XCD swizzle: 896 = 8*112; contiguous tiles per XCD
    const int b  = blockIdx.x;
    const int w  = (b & 7) * 112 + (b >> 3);
    const int n  = w / 28;
    const int r0 = (w % 28) * 2;        // output row base

    // ---- stage region (padded rows r0..r0+3, contiguous in xqp) ----
    // LDS granule (pix,ch) <- global granule (pix, ch^(pix&7))
    {
        const signed char* rsrc = xqp + ((size_t)n * PIMG + r0 * HP) * 256;
        const int base = wid * 64;      // wave-uniform part of granule idx
#pragma unroll
        for (int it = 0; it < 14; ++it) {
            int g   = it * 256 + base + lane;
            int pix = g >> 4, ch = g & 15;
            int src = pix * 256 + ((ch ^ (pix & 7)) << 4);
            gll16(rsrc + src, Bq + (it * 256 + base) * 16);
        }
        if (wid < 2) {                  // tail: granules 3584..3711
            int g   = 3584 + base + lane;
            int pix = g >> 4, ch = g & 15;
            int src = pix * 256 + ((ch ^ (pix & 7)) << 4);
            gll16(rsrc + src, Bq + (3584 + base) * 16);
        }
        VMCNT0();
        __syncthreads();
    }

    // ---- B pixel bases (local region pixel per output-px fragment j) ----
    int ppj[7];
#pragma unroll
    for (int j = 0; j < 7; ++j) {
        int opx  = j * 16 + l15;            // 0..111
        int orow = opx / 56, ocol = opx % 56;
        ppj[j] = (orow + 1) * HP + (ocol + 1);
    }

    // ---- A: per-wave 64 couts, 4 frags, direct global with reg prefetch ----
    const signed char* ap = wp2 + (wid * 64 + l15) * 64 + kg * 16;
    v4i aa[2][4];
#pragma unroll
    for (int i = 0; i < 4; ++i) aa[0][i] = *(const v4i*)(ap + i * 1024);

    v4i acc[4][7] = {};
    const signed char* aps = ap;            // current step base

    for (int t9 = 0; t9 < 9; ++t9) {
        const int pshift = (t9 / 3 - 1) * HP + (t9 % 3 - 1);
        int q[7];
#pragma unroll
        for (int j = 0; j < 7; ++j) {
            int pix = ppj[j] + pshift;
            q[j] = pix * 256 ^ (kg << 4) ^ ((pix & 7) << 4);
        }
#pragma unroll
        for (int kc = 0; kc < 4; ++kc) {
            const int cu = kc & 1, nx = cu ^ 1;     // static after unroll
            // prefetch A for next step (safe overrun into xqp at step 36)
            const signed char* an = aps + 16384;
#pragma unroll
            for (int i = 0; i < 4; ++i)
                aa[nx][i] = *(const v4i*)(an + i * 1024);

            __builtin_amdgcn_s_setprio(1);
#pragma unroll
            for (int j = 0; j < 7; ++j) {
                v4i bb = *(const v4i*)(Bq + (q[j] ^ (kc << 6)));
#pragma unroll
                for (int i = 0; i < 4; ++i)
                    acc[i][j] = __builtin_amdgcn_mfma_i32_16x16x64_i8(
                        aa[cu][i], bb, acc[i][j], 0, 0, 0);
            }
            __builtin_amdgcn_s_setprio(0);
            aps = an;
        }
    }

    // ---- epilogue: y = acc * (act_s * scale[c]) + bias[c], NCHW f32 ----
    const float a_s = act_s_p[0];
    const int hw0 = r0 * W56;
#pragma unroll
    for (int i = 0; i < 4; ++i) {
        int cb = wid * 64 + i * 16 + kg * 4;
        float sc[4], bi[4];
#pragma unroll
        for (int r = 0; r < 4; ++r) {
            sc[r] = a_s * scale[cb + r];
            bi[r] = bias[cb + r];
        }
#pragma unroll
        for (int j = 0; j < 7; ++j) {
            int px = j * 16 + l15;
#pragma unroll
            for (int r = 0; r < 4; ++r)
                out[((size_t)(n * COUT + cb + r)) * HW + hw0 + px] =
                    (float)acc[i][j][r] * sc[r] + bi[r];
        }
    }
}

// ---------------------------------------------------------------------------
extern "C" void kernel_launch(void* const* d_in, const int* in_sizes, int n_in,
                              void* d_out, int out_size, void* d_ws, size_t ws_size,
                              hipStream_t stream)
{
    const float* x     = (const float*)d_in[0];
    const int*   w_q   = (const int*)d_in[1];
    const float* s     = (const float*)d_in[2];
    const float* bias  = (const float*)d_in[3];
    const float* act_s = (const float*)d_in[4];

    signed char* wp2 = (signed char*)d_ws;                 // weights first
    signed char* xqp = (signed char*)d_ws + WP_BYTES;      // then padded xq

    zero_border<<<(NIMG * 228 * 16 + 255) / 256, 256, 0, stream>>>((v4i*)xqp);
    quantize_pad<<<dim3(49, 4, NIMG), 256, 0, stream>>>(x, xqp);
    repack_w<<<dim3(WP_BYTES / 256), 256, 0, stream>>>(w_q, wp2);
    bitconv_conv<<<dim3(NIMG * 28), 256, 0, stream>>>(
        xqp, wp2, s, bias, act_s, (float*)d_out);
}